// Round 13
// baseline (250.760 us; speedup 1.0000x reference)
//
#include <hip/hip_runtime.h>
#include <math.h>

#define Bn 128
#define Sn 200
#define NC3n 4000
#define GRUB Bn                 // 128 GRU blocks (1 wave, 1 row each)
#define FILLB (Bn * 6)          // 768 fill blocks, (b, t-sixth)

__device__ __forceinline__ float fexp(float x) { return __builtin_amdgcn_exp2f(x * 1.44269504f); }
__device__ __forceinline__ float frcp(float x) { return __builtin_amdgcn_rcpf(x); }
__device__ __forceinline__ float fsig(float x) { return frcp(1.f + fexp(-x)); }
__device__ __forceinline__ float rlanef(float v, int k) {
    return __int_as_float(__builtin_amdgcn_readlane(__float_as_int(v), k));
}

struct GruLds {                 // ~2.7 KB
    float hbc[64];              // h broadcast strip
    float pP[Sn];               // mlp1 per-step scalar
    float gam[Sn];
    int   r[Sn];
};
struct FillLds {                // ~6.2 KB
    float gam[Sn], val[Sn];
    int   r[Sn], c3[Sn], succ[Sn], root[Sn];
    float A[64], Bv[64], C0[64], C1[64], W2[64];
    float l2b2;
};

__global__ __launch_bounds__(64, 1) void fused6_kernel(
    const int* __restrict__ c3_seq, const int* __restrict__ d_seq,
    const int* __restrict__ r_seq, const float* __restrict__ v_c3,
    const float* __restrict__ D_w, const float* __restrict__ v_d,
    const float* __restrict__ R_w, const float* __restrict__ W_ih,
    const float* __restrict__ W_hh, const float* __restrict__ b_ih,
    const float* __restrict__ b_hh,
    const float* __restrict__ l1_w1, const float* __restrict__ l1_b1,
    const float* __restrict__ l1_w2, const float* __restrict__ l1_b2,
    const float* __restrict__ l2_w1, const float* __restrict__ l2_b1,
    const float* __restrict__ l2_w2, const float* __restrict__ l2_b2,
    float* __restrict__ out_alpha, float* __restrict__ out_h,
    float* __restrict__ out_c3)
{
    __shared__ __align__(16) union { GruLds g; FillLds f; } S;

    const int tid = threadIdx.x;
    const int bid = blockIdx.x;

    if (bid < GRUB) {
        // ===== single-wave GRU + mlp1 + alpha: NO barriers, hg in registers =====
        const int b = bid, j = tid;
        for (int i = j; i < Sn; i += 64) {
            S.g.gam[i] = D_w[d_seq[b * Sn + i]];
            S.g.r[i]   = r_seq[b * Sn + i];
        }
        // xg fold: lane j computes exactly its own gate rows {j, 64+j, 128+j}
        float uu[3], ww0[3], ww1[3];
        #pragma unroll
        for (int g = 0; g < 3; ++g) {
            const float4* rp  = (const float4*)(W_ih + (size_t)(g * 64 + j) * 128);
            const float4* vd4 = (const float4*)v_d;
            const float4* q04 = (const float4*)R_w;
            const float4* q14 = (const float4*)(R_w + 64);
            float u = 0.f, w0 = 0.f, w1 = 0.f;
            #pragma unroll 4
            for (int k = 0; k < 16; ++k) {
                float4 a  = rp[k];
                float4 bb = rp[16 + k];
                float4 vd = vd4[k], q0 = q04[k], q1 = q14[k];
                u  += a.x*vd.x + a.y*vd.y + a.z*vd.z + a.w*vd.w;
                w0 += bb.x*q0.x + bb.y*q0.y + bb.z*q0.z + bb.w*q0.w;
                w1 += bb.x*q1.x + bb.y*q1.y + bb.z*q1.z + bb.w*q1.w;
            }
            float bih = b_ih[g * 64 + j];
            uu[g] = u; ww0[g] = w0 + bih; ww1[g] = w1 + bih;
        }
        // weights in registers: W_hh rows j / 64+j / 128+j, l1_w1 row j (256 VGPRs)
        float wr[64], wz[64], wn[64], l1r[64];
        {
            const float4* r0 = (const float4*)(W_hh + (size_t)j * 64);
            const float4* r1 = (const float4*)(W_hh + (size_t)(64 + j) * 64);
            const float4* r2 = (const float4*)(W_hh + (size_t)(128 + j) * 64);
            const float4* r3 = (const float4*)(l1_w1 + (size_t)j * 64);
            #pragma unroll
            for (int k = 0; k < 16; ++k) {
                float4 a = r0[k], c = r1[k], d = r2[k], e = r3[k];
                wr[4*k+0]=a.x; wr[4*k+1]=a.y; wr[4*k+2]=a.z; wr[4*k+3]=a.w;
                wz[4*k+0]=c.x; wz[4*k+1]=c.y; wz[4*k+2]=c.z; wz[4*k+3]=c.w;
                wn[4*k+0]=d.x; wn[4*k+1]=d.y; wn[4*k+2]=d.z; wn[4*k+3]=d.w;
                l1r[4*k+0]=e.x; l1r[4*k+1]=e.y; l1r[4*k+2]=e.z; l1r[4*k+3]=e.w;
            }
        }
        const float bhr = b_hh[j], bhz = b_hh[64 + j], bhn = b_hh[128 + j];
        const float l1b = l1_b1[j], l1w2v = l1_w2[j], l1b2c = l1_b2[0];

        float hgr = bhr, hgz = bhz, hgn = bhn;    // W_hh@h0 + b_hh, h0 = 0
        float vh = 0.f;
        float* outp = out_h + (size_t)b * Sn * 64 + j;
        float gamc = S.g.gam[0]; int rc = S.g.r[0];

        for (int t = 0; t < Sn; ++t) {
            float gam = gamc; int r = rc;
            // gates — hg values are per-lane registers (own rows)
            float rg = fsig(fmaf(gam, uu[0], r ? ww1[0] : ww0[0]) + hgr);
            float zg = fsig(fmaf(gam, uu[1], r ? ww1[1] : ww0[1]) + hgz);
            float e2 = fexp(2.f * (fmaf(gam, uu[2], r ? ww1[2] : ww0[2]) + rg * hgn));
            float ng = 1.f - 2.f * frcp(e2 + 1.f);     // tanh
            vh = (1.f - zg) * ng + zg * vh;
            outp[0] = vh; outp += 64;                  // fire-and-forget
            // broadcast h via strip; batch all 16 b128 reads
            S.g.hbc[j] = vh;
            float4 hreg[16];
            #pragma unroll
            for (int k = 0; k < 16; ++k)
                hreg[k] = *(const float4*)&S.g.hbc[k * 4];
            __builtin_amdgcn_sched_barrier(0);
            if (t + 1 < Sn) { gamc = S.g.gam[t + 1]; rc = S.g.r[t + 1]; }  // hidden under fmas
            float ar0=0,ar1=0,ar2=0,ar3=0, az0=0,az1=0,az2=0,az3=0;
            float an0=0,an1=0,an2=0,an3=0, am0=0,am1=0,am2=0,am3=0;
            #pragma unroll
            for (int k = 0; k < 16; ++k) {
                float4 h4 = hreg[k];
                ar0 = fmaf(wr[4*k+0], h4.x, ar0); ar1 = fmaf(wr[4*k+1], h4.y, ar1);
                ar2 = fmaf(wr[4*k+2], h4.z, ar2); ar3 = fmaf(wr[4*k+3], h4.w, ar3);
                az0 = fmaf(wz[4*k+0], h4.x, az0); az1 = fmaf(wz[4*k+1], h4.y, az1);
                az2 = fmaf(wz[4*k+2], h4.z, az2); az3 = fmaf(wz[4*k+3], h4.w, az3);
                an0 = fmaf(wn[4*k+0], h4.x, an0); an1 = fmaf(wn[4*k+1], h4.y, an1);
                an2 = fmaf(wn[4*k+2], h4.z, an2); an3 = fmaf(wn[4*k+3], h4.w, an3);
                am0 = fmaf(l1r[4*k+0], h4.x, am0); am1 = fmaf(l1r[4*k+1], h4.y, am1);
                am2 = fmaf(l1r[4*k+2], h4.z, am2); am3 = fmaf(l1r[4*k+3], h4.w, am3);
            }
            hgr = bhr + ((ar0+ar1)+(ar2+ar3));
            hgz = bhz + ((az0+az1)+(az2+az3));
            hgn = bhn + ((an0+an1)+(an2+an3));
            // mlp1 (off the recurrence path)
            float p = fmaxf(((am0+am1)+(am2+am3)) + l1b, 0.f) * l1w2v;
            p += __shfl_xor(p, 1);
            p += __shfl_xor(p, 2);
            p += __shfl_xor(p, 4);
            p += __shfl_xor(p, 8);
            p += __shfl_xor(p, 16);
            p += __shfl_xor(p, 32);
            if (j == 0) S.g.pP[t] = p;
        }
        // deferred alpha chain: preload into lanes, readlane-driven serial walk
        {
            const int j3 = (j < 8) ? (192 + j) : 199;
            float an0 = S.g.pP[j]       + l1b2c;
            float an1 = S.g.pP[64 + j]  + l1b2c;
            float an2 = S.g.pP[128 + j] + l1b2c;
            float an3 = S.g.pP[j3]      + l1b2c;
            float g0 = S.g.gam[j],       g1 = S.g.gam[64 + j];
            float g2 = S.g.gam[128 + j], g3 = S.g.gam[j3];
            int   r0 = S.g.r[j],         r1 = S.g.r[64 + j];
            int   r2 = S.g.r[128 + j],   r3 = S.g.r[j3];
            float alpha = 0.f;
            float* oa = out_alpha + b * Sn;
            for (int t = 0; t < Sn; ++t) {
                const int q = t >> 6, l = t & 63;
                float an, g; int rr;
                if (q == 0)      { an = rlanef(an0,l); g = rlanef(g0,l); rr = __builtin_amdgcn_readlane(r0,l); }
                else if (q == 1) { an = rlanef(an1,l); g = rlanef(g1,l); rr = __builtin_amdgcn_readlane(r1,l); }
                else if (q == 2) { an = rlanef(an2,l); g = rlanef(g2,l); rr = __builtin_amdgcn_readlane(r2,l); }
                else             { an = rlanef(an3,l); g = rlanef(g3,l); rr = __builtin_amdgcn_readlane(r3,l); }
                bool cond = (alpha - g) >= 0.f;
                alpha = rr ? (cond ? an : alpha) : (cond ? alpha : an);
                if (j == 0) oa[t] = alpha;
            }
        }
    } else {
        // ===== single-wave C3 chain + forward-fill: one (row, t-sixth), NO barriers =====
        const int fb = bid - GRUB;
        const int b  = fb / 6;
        const int sp = fb - b * 6;
        const int t0 = sp * 33 + (sp < 2 ? sp : 2);
        const int t1 = t0 + (sp < 2 ? 34 : 33);
        for (int i = tid; i < Sn; i += 64) {
            S.f.gam[i] = D_w[d_seq[b*Sn + i]];
            S.f.r[i]   = r_seq[b*Sn + i];
            S.f.c3[i]  = c3_seq[b*Sn + i];
        }
        {   // collapsed mlp2 constants, lane tid = row tid
            const float4* row4 = (const float4*)(l2_w1 + (size_t)tid * 192);
            const float4* vc4  = (const float4*)v_c3;
            const float4* vd4  = (const float4*)v_d;
            const float4* q04  = (const float4*)R_w;
            const float4* q14  = (const float4*)(R_w + 64);
            float a2=0.f, b2=0.f, c0=0.f, c1=0.f;
            #pragma unroll 4
            for (int k = 0; k < 16; ++k) {
                float4 ra = row4[k], rb = row4[16+k], rc = row4[32+k];
                float4 vc = vc4[k], vd = vd4[k], q0 = q04[k], q1 = q14[k];
                a2 += ra.x*vc.x + ra.y*vc.y + ra.z*vc.z + ra.w*vc.w;
                b2 += rb.x*vd.x + rb.y*vd.y + rb.z*vd.z + rb.w*vd.w;
                c0 += rc.x*q0.x + rc.y*q0.y + rc.z*q0.z + rc.w*q0.w;
                c1 += rc.x*q1.x + rc.y*q1.y + rc.z*q1.z + rc.w*q1.w;
            }
            S.f.A[tid]  = a2;
            S.f.Bv[tid] = b2;
            S.f.C0[tid] = c0 + l2_b1[tid];
            S.f.C1[tid] = c1 + l2_b1[tid];
            S.f.W2[tid] = l2_w2[tid];
            if (tid == 0) S.f.l2b2 = l2_b2[0];
        }
        for (int i = tid; i < Sn; i += 64) {
            int c = S.f.c3[i];
            int s = -1;
            for (int u = i + 1; u < Sn; ++u)
                if (S.f.c3[u] == c) { s = u; break; }
            S.f.succ[i] = s;
            int rt = 1;
            for (int u = 0; u < i; ++u)
                if (S.f.c3[u] == c) { rt = 0; break; }
            S.f.root[i] = rt;
        }
        {   // chain walk, 4 groups of 16 lanes
            const int g  = tid >> 4;
            const int l  = tid & 15;
            const int j0 = l * 4;
            float A0=S.f.A[j0],  A1=S.f.A[j0+1],  A2=S.f.A[j0+2],  A3=S.f.A[j0+3];
            float B0=S.f.Bv[j0], B1=S.f.Bv[j0+1], B2=S.f.Bv[j0+2], B3=S.f.Bv[j0+3];
            float C00=S.f.C0[j0],C01=S.f.C0[j0+1],C02=S.f.C0[j0+2],C03=S.f.C0[j0+3];
            float C10=S.f.C1[j0],C11=S.f.C1[j0+1],C12=S.f.C1[j0+2],C13=S.f.C1[j0+3];
            float W0=S.f.W2[j0], W1=S.f.W2[j0+1], W2v=S.f.W2[j0+2],W3=S.f.W2[j0+3];
            float l2b2 = S.f.l2b2;
            for (int tt = g; tt < Sn; tt += 4) {
                if (!S.f.root[tt]) continue;
                float beta = 0.f;
                int t = tt;
                while (t >= 0) {
                    float gam = S.f.gam[t];
                    int   r   = S.f.r[t];
                    float s = W0*fmaxf(A0*beta + B0*gam + (r ? C10 : C00), 0.f)
                            + W1*fmaxf(A1*beta + B1*gam + (r ? C11 : C01), 0.f)
                            + W2v*fmaxf(A2*beta + B2*gam + (r ? C12 : C02), 0.f)
                            + W3*fmaxf(A3*beta + B3*gam + (r ? C13 : C03), 0.f);
                    s += __shfl_xor(s, 1, 16);
                    s += __shfl_xor(s, 2, 16);
                    s += __shfl_xor(s, 4, 16);
                    s += __shfl_xor(s, 8, 16);
                    beta = s + l2b2;
                    if (l == 0) S.f.val[t] = beta;
                    t = S.f.succ[t];
                }
            }
        }
        // forward-fill: lane owns 16 cols {q*256 + tid*4}; 16x 1KB-contiguous stores/row
        float4 st0,st1,st2,st3,st4,st5,st6,st7,st8,st9,st10,st11,st12,st13,st14,st15;
        st0=st1=st2=st3=st4=st5=st6=st7=st8=st9=st10=st11=st12=st13=st14=st15
            = make_float4(0.f,0.f,0.f,0.f);
        const unsigned base = (unsigned)(tid * 4);
        #define FUPD() { unsigned rel = (unsigned)cc - base;                                 \
            if (rel < 4096u && (rel & 255u) < 4u) {                                          \
                const int q = rel >> 8, d = rel & 3; const float v = vv;                     \
                switch (q) {                                                                 \
                case 0:  st0.x=(d==0)?v:st0.x;  st0.y=(d==1)?v:st0.y;  st0.z=(d==2)?v:st0.z;  st0.w=(d==3)?v:st0.w;  break; \
                case 1:  st1.x=(d==0)?v:st1.x;  st1.y=(d==1)?v:st1.y;  st1.z=(d==2)?v:st1.z;  st1.w=(d==3)?v:st1.w;  break; \
                case 2:  st2.x=(d==0)?v:st2.x;  st2.y=(d==1)?v:st2.y;  st2.z=(d==2)?v:st2.z;  st2.w=(d==3)?v:st2.w;  break; \
                case 3:  st3.x=(d==0)?v:st3.x;  st3.y=(d==1)?v:st3.y;  st3.z=(d==2)?v:st3.z;  st3.w=(d==3)?v:st3.w;  break; \
                case 4:  st4.x=(d==0)?v:st4.x;  st4.y=(d==1)?v:st4.y;  st4.z=(d==2)?v:st4.z;  st4.w=(d==3)?v:st4.w;  break; \
                case 5:  st5.x=(d==0)?v:st5.x;  st5.y=(d==1)?v:st5.y;  st5.z=(d==2)?v:st5.z;  st5.w=(d==3)?v:st5.w;  break; \
                case 6:  st6.x=(d==0)?v:st6.x;  st6.y=(d==1)?v:st6.y;  st6.z=(d==2)?v:st6.z;  st6.w=(d==3)?v:st6.w;  break; \
                case 7:  st7.x=(d==0)?v:st7.x;  st7.y=(d==1)?v:st7.y;  st7.z=(d==2)?v:st7.z;  st7.w=(d==3)?v:st7.w;  break; \
                case 8:  st8.x=(d==0)?v:st8.x;  st8.y=(d==1)?v:st8.y;  st8.z=(d==2)?v:st8.z;  st8.w=(d==3)?v:st8.w;  break; \
                case 9:  st9.x=(d==0)?v:st9.x;  st9.y=(d==1)?v:st9.y;  st9.z=(d==2)?v:st9.z;  st9.w=(d==3)?v:st9.w;  break; \
                case 10: st10.x=(d==0)?v:st10.x; st10.y=(d==1)?v:st10.y; st10.z=(d==2)?v:st10.z; st10.w=(d==3)?v:st10.w; break; \
                case 11: st11.x=(d==0)?v:st11.x; st11.y=(d==1)?v:st11.y; st11.z=(d==2)?v:st11.z; st11.w=(d==3)?v:st11.w; break; \
                case 12: st12.x=(d==0)?v:st12.x; st12.y=(d==1)?v:st12.y; st12.z=(d==2)?v:st12.z; st12.w=(d==3)?v:st12.w; break; \
                case 13: st13.x=(d==0)?v:st13.x; st13.y=(d==1)?v:st13.y; st13.z=(d==2)?v:st13.z; st13.w=(d==3)?v:st13.w; break; \
                case 14: st14.x=(d==0)?v:st14.x; st14.y=(d==1)?v:st14.y; st14.z=(d==2)?v:st14.z; st14.w=(d==3)?v:st14.w; break; \
                default: st15.x=(d==0)?v:st15.x; st15.y=(d==1)?v:st15.y; st15.z=(d==2)?v:st15.z; st15.w=(d==3)?v:st15.w; break; \
                } } }
        for (int t = 0; t < t0; ++t) {          // pre-scan (no stores)
            int cc = S.f.c3[t]; float vv = S.f.val[t];
            FUPD()
        }
        float* rowp = out_c3 + (size_t)b * Sn * NC3n + (size_t)t0 * NC3n;
        for (int t = t0; t < t1; ++t) {
            int cc = S.f.c3[t]; float vv = S.f.val[t];
            FUPD()
            float* lp = rowp + tid * 4;
            *(float4*)(lp + 0*256)  = st0;
            *(float4*)(lp + 1*256)  = st1;
            *(float4*)(lp + 2*256)  = st2;
            *(float4*)(lp + 3*256)  = st3;
            *(float4*)(lp + 4*256)  = st4;
            *(float4*)(lp + 5*256)  = st5;
            *(float4*)(lp + 6*256)  = st6;
            *(float4*)(lp + 7*256)  = st7;
            *(float4*)(lp + 8*256)  = st8;
            *(float4*)(lp + 9*256)  = st9;
            *(float4*)(lp + 10*256) = st10;
            *(float4*)(lp + 11*256) = st11;
            *(float4*)(lp + 12*256) = st12;
            *(float4*)(lp + 13*256) = st13;
            *(float4*)(lp + 14*256) = st14;
            if (tid < 40) *(float4*)(lp + 15*256) = st15;   // cols 3840+tid*4 < 4000
            rowp += NC3n;
        }
    }
}

extern "C" void kernel_launch(void* const* d_in, const int* in_sizes, int n_in,
                              void* d_out, int out_size, void* d_ws, size_t ws_size,
                              hipStream_t stream)
{
    const int*   c3_seq = (const int*)  d_in[0];
    const int*   d_seq  = (const int*)  d_in[1];
    const int*   r_seq  = (const int*)  d_in[2];
    const float* v_c3   = (const float*)d_in[3];
    const float* D_w    = (const float*)d_in[4];
    const float* v_d    = (const float*)d_in[5];
    const float* R_w    = (const float*)d_in[6];
    const float* W_ih   = (const float*)d_in[7];
    const float* W_hh   = (const float*)d_in[8];
    const float* b_ih   = (const float*)d_in[9];
    const float* b_hh   = (const float*)d_in[10];
    const float* l1_w1  = (const float*)d_in[11];
    const float* l1_b1  = (const float*)d_in[12];
    const float* l1_w2  = (const float*)d_in[13];
    const float* l1_b2  = (const float*)d_in[14];
    const float* l2_w1  = (const float*)d_in[15];
    const float* l2_b1  = (const float*)d_in[16];
    const float* l2_w2  = (const float*)d_in[17];
    const float* l2_b2  = (const float*)d_in[18];

    float* out_alpha = (float*)d_out;
    float* out_h     = out_alpha + Bn*Sn;
    float* out_c3    = out_h + (size_t)Bn*Sn*64;

    fused6_kernel<<<GRUB + FILLB, 64, 0, stream>>>(
        c3_seq, d_seq, r_seq, v_c3, D_w, v_d, R_w, W_ih, W_hh, b_ih, b_hh,
        l1_w1, l1_b1, l1_w2, l1_b2, l2_w1, l2_b1, l2_w2, l2_b2,
        out_alpha, out_h, out_c3);
}

// Round 14
// 183.753 us; speedup vs baseline: 1.3647x; 1.3647x over previous
//
#include <hip/hip_runtime.h>
#include <math.h>

#define Bn 128
#define Sn 200
#define NC3n 4000
#define GRUB 64                 // 64 GRU blocks x 2 rows = 128 rows
#define FILLB (Bn * 2)          // 256 fill blocks, (b, t-half)

__device__ __forceinline__ float fexp(float x) { return __builtin_amdgcn_exp2f(x * 1.44269504f); }
__device__ __forceinline__ float frcp(float x) { return __builtin_amdgcn_rcpf(x); }
__device__ __forceinline__ float fsig(float x) { return frcp(1.f + fexp(-x)); }
__device__ __forceinline__ float rlanef(float v, int k) {
    return __int_as_float(__builtin_amdgcn_readlane(__float_as_int(v), k));
}

#define UPD(q, cbase) { int d = cc - (cbase); if ((unsigned)d < 4u) { \
    q.x = (d==0)?v:q.x; q.y = (d==1)?v:q.y; q.z = (d==2)?v:q.z; q.w = (d==3)?v:q.w; } }

struct GruLds {                 // ~17.6 KB (x2 rows = 35.2 KB)
    float ring[2][16][64];      // out_h staging
    float pPart[Sn][4];         // mlp1 16-lane partials
    float hbc[4][64];           // per-role-wave h broadcast strips
    float u[192], w0[192], w1[192];
    float hg[2][192];           // ping-pong W_hh@h + b_hh
    float gam[Sn];
    int   r[Sn];
};
struct FillLds {                // ~6.2 KB
    float gam[Sn], val[Sn];
    int   r[Sn], c3[Sn], succ[Sn], root[Sn];
    float A[64], Bv[64], C0[64], C1[64], W2[64];
    float l2b2;
};

__global__ __launch_bounds__(512, 1) void fused7_kernel(
    const int* __restrict__ c3_seq, const int* __restrict__ d_seq,
    const int* __restrict__ r_seq, const float* __restrict__ v_c3,
    const float* __restrict__ D_w, const float* __restrict__ v_d,
    const float* __restrict__ R_w, const float* __restrict__ W_ih,
    const float* __restrict__ W_hh, const float* __restrict__ b_ih,
    const float* __restrict__ b_hh,
    const float* __restrict__ l1_w1, const float* __restrict__ l1_b1,
    const float* __restrict__ l1_w2, const float* __restrict__ l1_b2,
    const float* __restrict__ l2_w1, const float* __restrict__ l2_b1,
    const float* __restrict__ l2_w2, const float* __restrict__ l2_b2,
    float* __restrict__ out_alpha, float* __restrict__ out_h,
    float* __restrict__ out_c3)
{
    __shared__ __align__(16) union { GruLds g[2]; FillLds f; } S;

    const int tid = threadIdx.x;
    const int bid = blockIdx.x;

    if (bid < GRUB) {
        // ===== GRU + mlp1 + alpha: 2 rows/block (8 waves), 4 role waves per row =====
        const int rw   = tid >> 8;          // row within block (waves 0-3 / 4-7)
        const int role = (tid >> 6) & 3;    // 0=r,1=z,2=n,3=mlp1
        const int j    = tid & 63;
        const int ht   = tid & 255;         // thread index within the row's half
        const int b    = bid * 2 + rw;
        GruLds& G = S.g[rw];

        if (ht < Sn) {
            G.gam[ht] = D_w[d_seq[b * Sn + ht]];
            G.r[ht]   = r_seq[b * Sn + ht];
        }
        // fold xg: u = W_ih[rho,:64]@v_d ; w0/w1 = W_ih[rho,64:]@R_w[r] + b_ih[rho]
        if (ht < 192) {
            const float4* rp  = (const float4*)(W_ih + (size_t)ht * 128);
            const float4* vd4 = (const float4*)v_d;
            const float4* q04 = (const float4*)R_w;
            const float4* q14 = (const float4*)(R_w + 64);
            float u = 0.f, w0 = 0.f, w1 = 0.f;
            #pragma unroll 4
            for (int k = 0; k < 16; ++k) {
                float4 a  = rp[k];
                float4 bb = rp[16 + k];
                float4 vd = vd4[k], q0 = q04[k], q1 = q14[k];
                u  += a.x*vd.x + a.y*vd.y + a.z*vd.z + a.w*vd.w;
                w0 += bb.x*q0.x + bb.y*q0.y + bb.z*q0.z + bb.w*q0.w;
                w1 += bb.x*q1.x + bb.y*q1.y + bb.z*q1.z + bb.w*q1.w;
            }
            float bih = b_ih[ht];
            G.u[ht]  = u;
            G.w0[ht] = w0 + bih;
            G.w1[ht] = w1 + bih;
        }
        // per-wave weight row: role<3 -> W_hh row role*64+j ; role==3 -> l1_w1 row j
        float w[64];
        {
            const float* src = (role < 3) ? (W_hh + (size_t)(role * 64 + j) * 64)
                                          : (l1_w1 + (size_t)j * 64);
            const float4* s4 = (const float4*)src;
            #pragma unroll
            for (int k = 0; k < 16; ++k) {
                float4 v = s4[k];
                w[4*k+0]=v.x; w[4*k+1]=v.y; w[4*k+2]=v.z; w[4*k+3]=v.w;
            }
        }
        float bown = 0.f, l1b = 0.f, l1w2v = 0.f;
        if (role < 3) {
            bown = b_hh[role * 64 + j];
            G.hg[0][role * 64 + j] = bown;      // h0=0 -> hg(t=0)=b_hh
        } else {
            l1b = l1_b1[j]; l1w2v = l1_w2[j];
        }
        const float l1b2c = l1_b2[0];
        __syncthreads();

        const float uj  = G.u[j],  u1  = G.u[64+j],  u2  = G.u[128+j];
        const float w00 = G.w0[j], w01 = G.w0[64+j], w02 = G.w0[128+j];
        const float w10 = G.w1[j], w11 = G.w1[64+j], w12 = G.w1[128+j];

        float vh = 0.f;
        float* outh_base = out_h + (size_t)b * Sn * 64;
        const int rloc = 4 * role + (j >> 4);
        const int cloc = (j & 15) * 4;

        for (int t = 0; t < Sn; ++t) {
            if (t && (t & 15) == 0) {           // flush completed ring half
                const int hb = ((t >> 4) & 1) ^ 1;
                float4 v4 = *(const float4*)&G.ring[hb][rloc][cloc];
                *(float4*)(outh_base + (size_t)(t - 16 + rloc) * 64 + cloc) = v4;
            }
            const int buf = t & 1;
            float gam = G.gam[t];
            int   r   = G.r[t];
            float hr = G.hg[buf][j], hz = G.hg[buf][64+j], hn = G.hg[buf][128+j];
            float rg = fsig(fmaf(gam, uj, r ? w10 : w00) + hr);
            float zg = fsig(fmaf(gam, u1, r ? w11 : w01) + hz);
            float e2 = fexp(2.f * (fmaf(gam, u2, r ? w12 : w02) + rg * hn));
            float ng = 1.f - 2.f * frcp(e2 + 1.f);   // tanh
            vh = (1.f - zg) * ng + zg * vh;
            // self-broadcast h: write strip, BATCH all 16 b128 reads (single wait)
            G.hbc[role][j] = vh;
            float4 hreg[16];
            #pragma unroll
            for (int k = 0; k < 16; ++k)
                hreg[k] = *(const float4*)&G.hbc[role][k * 4];
            __builtin_amdgcn_sched_barrier(0);  // keep loads batched above the fmas
            float a0=0.f, a1=0.f, a2=0.f, a3=0.f;
            #pragma unroll
            for (int k = 0; k < 16; ++k) {
                a0 = fmaf(w[4*k+0], hreg[k].x, a0);
                a1 = fmaf(w[4*k+1], hreg[k].y, a1);
                a2 = fmaf(w[4*k+2], hreg[k].z, a2);
                a3 = fmaf(w[4*k+3], hreg[k].w, a3);
            }
            float dot = (a0 + a1) + (a2 + a3);
            if (role < 3) {
                G.hg[buf ^ 1][role * 64 + j] = bown + dot;
            } else {
                float p = fmaxf(dot + l1b, 0.f) * l1w2v;
                p += __shfl_xor(p, 1);
                p += __shfl_xor(p, 2);
                p += __shfl_xor(p, 4);
                p += __shfl_xor(p, 8);
                if ((j & 15) == 0) G.pPart[t][j >> 4] = p;
                G.ring[(t >> 4) & 1][t & 15][j] = vh;
            }
            __syncthreads();
        }
        if (role < 2) {                         // rows 192..199 from ring[0][0..7]
            float4 v4 = *(const float4*)&G.ring[0][rloc][cloc];
            *(float4*)(outh_base + (size_t)(192 + rloc) * 64 + cloc) = v4;
        }
        // deferred alpha chain: parallel an-preload + readlane-driven serial walk
        if (role == 3) {
            float4 pp0 = *(const float4*)&G.pPart[j][0];
            float4 pp1 = *(const float4*)&G.pPart[64 + j][0];
            float4 pp2 = *(const float4*)&G.pPart[128 + j][0];
            const int j3 = (j < 8) ? (192 + j) : 199;
            float4 pp3 = *(const float4*)&G.pPart[j3][0];
            float an0 = ((pp0.x+pp0.y)+(pp0.z+pp0.w)) + l1b2c;
            float an1 = ((pp1.x+pp1.y)+(pp1.z+pp1.w)) + l1b2c;
            float an2 = ((pp2.x+pp2.y)+(pp2.z+pp2.w)) + l1b2c;
            float an3 = ((pp3.x+pp3.y)+(pp3.z+pp3.w)) + l1b2c;
            float g0 = G.gam[j],       g1 = G.gam[64 + j];
            float g2 = G.gam[128 + j], g3 = G.gam[j3];
            int   r0 = G.r[j],         r1 = G.r[64 + j];
            int   r2 = G.r[128 + j],   r3 = G.r[j3];
            float alpha = 0.f;
            float* oa = out_alpha + b * Sn;
            for (int t = 0; t < Sn; ++t) {
                const int q = t >> 6, l = t & 63;
                float an, g; int rr;
                if (q == 0)      { an = rlanef(an0,l); g = rlanef(g0,l); rr = __builtin_amdgcn_readlane(r0,l); }
                else if (q == 1) { an = rlanef(an1,l); g = rlanef(g1,l); rr = __builtin_amdgcn_readlane(r1,l); }
                else if (q == 2) { an = rlanef(an2,l); g = rlanef(g2,l); rr = __builtin_amdgcn_readlane(r2,l); }
                else             { an = rlanef(an3,l); g = rlanef(g3,l); rr = __builtin_amdgcn_readlane(r3,l); }
                bool cond = (alpha - g) >= 0.f;
                alpha = rr ? (cond ? an : alpha) : (cond ? alpha : an);
                if (j == 0) oa[t] = alpha;
            }
        }
    } else {
        // ===== C3 chain + full-row streaming fill: one (row, t-half), 500 threads =====
        const int fb   = bid - GRUB;
        const int b    = fb >> 1;
        const int half = fb & 1;
        if (tid < Sn) {
            S.f.gam[tid] = D_w[d_seq[b*Sn + tid]];
            S.f.r[tid]   = r_seq[b*Sn + tid];
            S.f.c3[tid]  = c3_seq[b*Sn + tid];
        }
        if (tid < 64) {
            const float4* row4 = (const float4*)(l2_w1 + (size_t)tid * 192);
            const float4* vc4  = (const float4*)v_c3;
            const float4* vd4  = (const float4*)v_d;
            const float4* q04  = (const float4*)R_w;
            const float4* q14  = (const float4*)(R_w + 64);
            float a2=0.f, b2=0.f, c0=0.f, c1=0.f;
            #pragma unroll 4
            for (int k = 0; k < 16; ++k) {
                float4 ra = row4[k], rb = row4[16+k], rc = row4[32+k];
                float4 vc = vc4[k], vd = vd4[k], q0 = q04[k], q1 = q14[k];
                a2 += ra.x*vc.x + ra.y*vc.y + ra.z*vc.z + ra.w*vc.w;
                b2 += rb.x*vd.x + rb.y*vd.y + rb.z*vd.z + rb.w*vd.w;
                c0 += rc.x*q0.x + rc.y*q0.y + rc.z*q0.z + rc.w*q0.w;
                c1 += rc.x*q1.x + rc.y*q1.y + rc.z*q1.z + rc.w*q1.w;
            }
            S.f.A[tid]  = a2;
            S.f.Bv[tid] = b2;
            S.f.C0[tid] = c0 + l2_b1[tid];
            S.f.C1[tid] = c1 + l2_b1[tid];
            S.f.W2[tid] = l2_w2[tid];
        }
        if (tid == 0) S.f.l2b2 = l2_b2[0];
        __syncthreads();
        if (tid < Sn) {
            int c = S.f.c3[tid];
            int s = -1;
            for (int u = tid + 1; u < Sn; ++u)
                if (S.f.c3[u] == c) { s = u; break; }
            S.f.succ[tid] = s;
            int rt = 1;
            for (int u = 0; u < tid; ++u)
                if (S.f.c3[u] == c) { rt = 0; break; }
            S.f.root[tid] = rt;
        }
        __syncthreads();
        if (tid < 256) {   // chain walk, 16-lane groups
            const int g  = tid >> 4;
            const int l  = tid & 15;
            const int j0 = l * 4;
            float A0=S.f.A[j0],  A1=S.f.A[j0+1],  A2=S.f.A[j0+2],  A3=S.f.A[j0+3];
            float B0=S.f.Bv[j0], B1=S.f.Bv[j0+1], B2=S.f.Bv[j0+2], B3=S.f.Bv[j0+3];
            float C00=S.f.C0[j0],C01=S.f.C0[j0+1],C02=S.f.C0[j0+2],C03=S.f.C0[j0+3];
            float C10=S.f.C1[j0],C11=S.f.C1[j0+1],C12=S.f.C1[j0+2],C13=S.f.C1[j0+3];
            float W0=S.f.W2[j0], W1=S.f.W2[j0+1], W2v=S.f.W2[j0+2],W3=S.f.W2[j0+3];
            float l2b2 = S.f.l2b2;
            for (int t0 = g; t0 < Sn; t0 += 16) {
                if (!S.f.root[t0]) continue;
                float beta = 0.f;
                int t = t0;
                while (t >= 0) {
                    float gam = S.f.gam[t];
                    int   r   = S.f.r[t];
                    float s = W0*fmaxf(A0*beta + B0*gam + (r ? C10 : C00), 0.f)
                            + W1*fmaxf(A1*beta + B1*gam + (r ? C11 : C01), 0.f)
                            + W2v*fmaxf(A2*beta + B2*gam + (r ? C12 : C02), 0.f)
                            + W3*fmaxf(A3*beta + B3*gam + (r ? C13 : C03), 0.f);
                    s += __shfl_xor(s, 1, 16);
                    s += __shfl_xor(s, 2, 16);
                    s += __shfl_xor(s, 4, 16);
                    s += __shfl_xor(s, 8, 16);
                    beta = s + l2b2;
                    if (l == 0) S.f.val[t] = beta;
                    t = S.f.succ[t];
                }
            }
        }
        __syncthreads();
        // fill: thread owns 2 f4 columns; whole 16KB row stored contiguously per t
        if (tid < 500) {
            const int cA = tid * 4, cB = 2000 + tid * 4;
            float4 qA = make_float4(0.f,0.f,0.f,0.f), qB = qA;
            const int t0 = half * 100;
            for (int t = 0; t < t0; ++t) {      // pre-scan (no stores)
                int cc = S.f.c3[t]; float v = S.f.val[t];
                UPD(qA, cA) UPD(qB, cB)
            }
            float* rowp = out_c3 + (size_t)b * Sn * NC3n + (size_t)t0 * NC3n;
            for (int t = t0; t < t0 + 100; ++t) {
                int cc = S.f.c3[t]; float v = S.f.val[t];
                UPD(qA, cA) UPD(qB, cB)
                *(float4*)(rowp + cA) = qA;
                *(float4*)(rowp + cB) = qB;
                rowp += NC3n;
            }
        }
    }
}

extern "C" void kernel_launch(void* const* d_in, const int* in_sizes, int n_in,
                              void* d_out, int out_size, void* d_ws, size_t ws_size,
                              hipStream_t stream)
{
    const int*   c3_seq = (const int*)  d_in[0];
    const int*   d_seq  = (const int*)  d_in[1];
    const int*   r_seq  = (const int*)  d_in[2];
    const float* v_c3   = (const float*)d_in[3];
    const float* D_w    = (const float*)d_in[4];
    const float* v_d    = (const float*)d_in[5];
    const float* R_w    = (const float*)d_in[6];
    const float* W_ih   = (const float*)d_in[7];
    const float* W_hh   = (const float*)d_in[8];
    const float* b_ih   = (const float*)d_in[9];
    const float* b_hh   = (const float*)d_in[10];
    const float* l1_w1  = (const float*)d_in[11];
    const float* l1_b1  = (const float*)d_in[12];
    const float* l1_w2  = (const float*)d_in[13];
    const float* l1_b2  = (const float*)d_in[14];
    const float* l2_w1  = (const float*)d_in[15];
    const float* l2_b1  = (const float*)d_in[16];
    const float* l2_w2  = (const float*)d_in[17];
    const float* l2_b2  = (const float*)d_in[18];

    float* out_alpha = (float*)d_out;
    float* out_h     = out_alpha + Bn*Sn;
    float* out_c3    = out_h + (size_t)Bn*Sn*64;

    fused7_kernel<<<GRUB + FILLB, 512, 0, stream>>>(
        c3_seq, d_seq, r_seq, v_c3, D_w, v_d, R_w, W_ih, W_hh, b_ih, b_hh,
        l1_w1, l1_b1, l1_w2, l1_b2, l2_w1, l2_b1, l2_w2, l2_b2,
        out_alpha, out_h, out_c3);
}

// Round 15
// 160.004 us; speedup vs baseline: 1.5672x; 1.1484x over previous
//
#include <hip/hip_runtime.h>
#include <math.h>

#define Bn 128
#define Sn 200
#define NC3n 4000
#define GRUB Bn                 // 128 GRU blocks, 1 row each
#define FILLB (Bn * 4)          // 512 fill blocks, (b, quarter)

__device__ __forceinline__ float fexp(float x) { return __builtin_amdgcn_exp2f(x * 1.44269504f); }
__device__ __forceinline__ float frcp(float x) { return __builtin_amdgcn_rcpf(x); }
__device__ __forceinline__ float fsig(float x) { return frcp(1.f + fexp(-x)); }
__device__ __forceinline__ float rlanef(float v, int k) {
    return __int_as_float(__builtin_amdgcn_readlane(__float_as_int(v), k));
}

#define UPD(q, cbase) { int d = cc - (cbase); if ((unsigned)d < 4u) { \
    q.x = (d==0)?v:q.x; q.y = (d==1)?v:q.y; q.z = (d==2)?v:q.z; q.w = (d==3)?v:q.w; } }

struct GruLds {                 // ~17.5 KB
    float ring[2][16][64];      // out_h staging (8 KB)
    float pPart[Sn][4];         // mlp1 16-lane partials
    float hbc[4][64];           // per-wave h broadcast strips
    float u[192], w0[192], w1[192];
    float hg[2][192];           // ping-pong W_hh@h + b_hh
    float gam[Sn];
    int   r[Sn];
};
struct FillLds {                // ~6.2 KB
    float gam[Sn], val[Sn];
    int   r[Sn], c3[Sn], succ[Sn], root[Sn];
    float A[64], Bv[64], C0[64], C1[64], W2[64];
    float l2b2;
};

__global__ __launch_bounds__(256, 2) void fused8_kernel(
    const int* __restrict__ c3_seq, const int* __restrict__ d_seq,
    const int* __restrict__ r_seq, const float* __restrict__ v_c3,
    const float* __restrict__ D_w, const float* __restrict__ v_d,
    const float* __restrict__ R_w, const float* __restrict__ W_ih,
    const float* __restrict__ W_hh, const float* __restrict__ b_ih,
    const float* __restrict__ b_hh,
    const float* __restrict__ l1_w1, const float* __restrict__ l1_b1,
    const float* __restrict__ l1_w2, const float* __restrict__ l1_b2,
    const float* __restrict__ l2_w1, const float* __restrict__ l2_b1,
    const float* __restrict__ l2_w2, const float* __restrict__ l2_b2,
    float* __restrict__ out_alpha, float* __restrict__ out_h,
    float* __restrict__ out_c3)
{
    __shared__ __align__(16) union { GruLds g; FillLds f; } S;

    const int tid = threadIdx.x;
    const int bid = blockIdx.x;

    if (bid < GRUB) {
        // ===== GRU + mlp1 + alpha: 1 row, 4 role waves, 1 barrier/step =====
        __builtin_amdgcn_s_setprio(1);
        const int b    = bid;
        const int role = tid >> 6;          // 0=r,1=z,2=n,3=mlp1
        const int j    = tid & 63;

        if (tid < Sn) {
            S.g.gam[tid] = D_w[d_seq[b * Sn + tid]];
            S.g.r[tid]   = r_seq[b * Sn + tid];
        }
        // fold xg: u = W_ih[rho,:64]@v_d ; w0/w1 = W_ih[rho,64:]@R_w[r] + b_ih[rho]
        if (tid < 192) {
            const float4* rp  = (const float4*)(W_ih + (size_t)tid * 128);
            const float4* vd4 = (const float4*)v_d;
            const float4* q04 = (const float4*)R_w;
            const float4* q14 = (const float4*)(R_w + 64);
            float u = 0.f, w0 = 0.f, w1 = 0.f;
            #pragma unroll 4
            for (int k = 0; k < 16; ++k) {
                float4 a  = rp[k];
                float4 bb = rp[16 + k];
                float4 vd = vd4[k], q0 = q04[k], q1 = q14[k];
                u  += a.x*vd.x + a.y*vd.y + a.z*vd.z + a.w*vd.w;
                w0 += bb.x*q0.x + bb.y*q0.y + bb.z*q0.z + bb.w*q0.w;
                w1 += bb.x*q1.x + bb.y*q1.y + bb.z*q1.z + bb.w*q1.w;
            }
            float bih = b_ih[tid];
            S.g.u[tid]  = u;
            S.g.w0[tid] = w0 + bih;
            S.g.w1[tid] = w1 + bih;
        }
        // per-wave weight row: role<3 -> W_hh row role*64+j ; role==3 -> l1_w1 row j
        float w[64];
        {
            const float* src = (role < 3) ? (W_hh + (size_t)(role * 64 + j) * 64)
                                          : (l1_w1 + (size_t)j * 64);
            const float4* s4 = (const float4*)src;
            #pragma unroll
            for (int k = 0; k < 16; ++k) {
                float4 v = s4[k];
                w[4*k+0]=v.x; w[4*k+1]=v.y; w[4*k+2]=v.z; w[4*k+3]=v.w;
            }
        }
        // PIN the weights into VGPRs: the asm "modifies" each element, so the
        // loop below must consume the register values — the compiler can no
        // longer sink/rematerialize the global loads into the 200-step loop
        // (R9/R13 counters: VGPR=68/FETCH=815MB proved it was re-loading).
        #pragma unroll
        for (int k = 0; k < 16; ++k)
            asm volatile("" : "+v"(w[4*k+0]), "+v"(w[4*k+1]), "+v"(w[4*k+2]), "+v"(w[4*k+3]));

        float bown = 0.f, l1b = 0.f, l1w2v = 0.f;
        if (role < 3) {
            bown = b_hh[role * 64 + j];
            S.g.hg[0][role * 64 + j] = bown;    // h0=0 -> hg(t=0)=b_hh
        } else {
            l1b = l1_b1[j]; l1w2v = l1_w2[j];
        }
        const float l1b2c = l1_b2[0];
        __syncthreads();                        // prologue barrier

        const float uj  = S.g.u[j],  u1  = S.g.u[64+j],  u2  = S.g.u[128+j];
        const float w00 = S.g.w0[j], w01 = S.g.w0[64+j], w02 = S.g.w0[128+j];
        const float w10 = S.g.w1[j], w11 = S.g.w1[64+j], w12 = S.g.w1[128+j];

        float vh = 0.f;
        float* outh_base = out_h + (size_t)b * Sn * 64;
        const int rloc = 4 * role + (j >> 4);
        const int cloc = (j & 15) * 4;

        for (int t = 0; t < Sn; ++t) {
            if (t && (t & 15) == 0) {           // flush completed ring half
                const int hb = ((t >> 4) & 1) ^ 1;
                float4 v4 = *(const float4*)&S.g.ring[hb][rloc][cloc];
                *(float4*)(outh_base + (size_t)(t - 16 + rloc) * 64 + cloc) = v4;
            }
            const int buf = t & 1;
            float gam = S.g.gam[t];
            int   r   = S.g.r[t];
            float hr = S.g.hg[buf][j], hz = S.g.hg[buf][64+j], hn = S.g.hg[buf][128+j];
            float rg = fsig(fmaf(gam, uj, r ? w10 : w00) + hr);
            float zg = fsig(fmaf(gam, u1, r ? w11 : w01) + hz);
            float e2 = fexp(2.f * (fmaf(gam, u2, r ? w12 : w02) + rg * hn));
            float ng = 1.f - 2.f * frcp(e2 + 1.f);   // tanh
            vh = (1.f - zg) * ng + zg * vh;
            // self-broadcast h: write strip, BATCH all 16 b128 reads (single wait)
            S.g.hbc[role][j] = vh;
            float4 hreg[16];
            #pragma unroll
            for (int k = 0; k < 16; ++k)
                hreg[k] = *(const float4*)&S.g.hbc[role][k * 4];
            __builtin_amdgcn_sched_barrier(0);  // keep loads batched above the fmas
            float a0=0.f, a1=0.f, a2=0.f, a3=0.f;
            #pragma unroll
            for (int k = 0; k < 16; ++k) {
                a0 = fmaf(w[4*k+0], hreg[k].x, a0);
                a1 = fmaf(w[4*k+1], hreg[k].y, a1);
                a2 = fmaf(w[4*k+2], hreg[k].z, a2);
                a3 = fmaf(w[4*k+3], hreg[k].w, a3);
            }
            float dot = (a0 + a1) + (a2 + a3);
            if (role < 3) {
                S.g.hg[buf ^ 1][role * 64 + j] = bown + dot;
            } else {
                float p = fmaxf(dot + l1b, 0.f) * l1w2v;
                p += __shfl_xor(p, 1);
                p += __shfl_xor(p, 2);
                p += __shfl_xor(p, 4);
                p += __shfl_xor(p, 8);
                if ((j & 15) == 0) S.g.pPart[t][j >> 4] = p;
                S.g.ring[(t >> 4) & 1][t & 15][j] = vh;
            }
            __syncthreads();
        }
        if (role < 2) {                         // rows 192..199 from ring[0][0..7]
            float4 v4 = *(const float4*)&S.g.ring[0][rloc][cloc];
            *(float4*)(outh_base + (size_t)(192 + rloc) * 64 + cloc) = v4;
        }
        // deferred alpha chain: parallel an-preload + readlane-driven serial walk
        if (role == 3) {
            float4 pp0 = *(const float4*)&S.g.pPart[j][0];
            float4 pp1 = *(const float4*)&S.g.pPart[64 + j][0];
            float4 pp2 = *(const float4*)&S.g.pPart[128 + j][0];
            const int j3 = (j < 8) ? (192 + j) : 199;
            float4 pp3 = *(const float4*)&S.g.pPart[j3][0];
            float an0 = ((pp0.x+pp0.y)+(pp0.z+pp0.w)) + l1b2c;
            float an1 = ((pp1.x+pp1.y)+(pp1.z+pp1.w)) + l1b2c;
            float an2 = ((pp2.x+pp2.y)+(pp2.z+pp2.w)) + l1b2c;
            float an3 = ((pp3.x+pp3.y)+(pp3.z+pp3.w)) + l1b2c;
            float g0 = S.g.gam[j],       g1 = S.g.gam[64 + j];
            float g2 = S.g.gam[128 + j], g3 = S.g.gam[j3];
            int   r0 = S.g.r[j],         r1 = S.g.r[64 + j];
            int   r2 = S.g.r[128 + j],   r3 = S.g.r[j3];
            float alpha = 0.f;
            float* oa = out_alpha + b * Sn;
            for (int t = 0; t < Sn; ++t) {
                const int q = t >> 6, l = t & 63;
                float an, g; int rr;
                if (q == 0)      { an = rlanef(an0,l); g = rlanef(g0,l); rr = __builtin_amdgcn_readlane(r0,l); }
                else if (q == 1) { an = rlanef(an1,l); g = rlanef(g1,l); rr = __builtin_amdgcn_readlane(r1,l); }
                else if (q == 2) { an = rlanef(an2,l); g = rlanef(g2,l); rr = __builtin_amdgcn_readlane(r2,l); }
                else             { an = rlanef(an3,l); g = rlanef(g3,l); rr = __builtin_amdgcn_readlane(r3,l); }
                bool cond = (alpha - g) >= 0.f;
                alpha = rr ? (cond ? an : alpha) : (cond ? alpha : an);
                if (j == 0) oa[t] = alpha;
            }
        }
    } else {
        // ===== C3 chain + contiguous forward-fill: one (row, quarter) =====
        const int fb = bid - GRUB;
        const int b  = fb >> 2;
        const int qt = fb & 3;
        if (tid < Sn) {
            S.f.gam[tid] = D_w[d_seq[b*Sn + tid]];
            S.f.r[tid]   = r_seq[b*Sn + tid];
            S.f.c3[tid]  = c3_seq[b*Sn + tid];
        }
        if (tid < 64) {
            const float4* row4 = (const float4*)(l2_w1 + (size_t)tid * 192);
            const float4* vc4  = (const float4*)v_c3;
            const float4* vd4  = (const float4*)v_d;
            const float4* q04  = (const float4*)R_w;
            const float4* q14  = (const float4*)(R_w + 64);
            float a2=0.f, b2=0.f, c0=0.f, c1=0.f;
            #pragma unroll 4
            for (int k = 0; k < 16; ++k) {
                float4 ra = row4[k], rb = row4[16+k], rc = row4[32+k];
                float4 vc = vc4[k], vd = vd4[k], q0 = q04[k], q1 = q14[k];
                a2 += ra.x*vc.x + ra.y*vc.y + ra.z*vc.z + ra.w*vc.w;
                b2 += rb.x*vd.x + rb.y*vd.y + rb.z*vd.z + rb.w*vd.w;
                c0 += rc.x*q0.x + rc.y*q0.y + rc.z*q0.z + rc.w*q0.w;
                c1 += rc.x*q1.x + rc.y*q1.y + rc.z*q1.z + rc.w*q1.w;
            }
            S.f.A[tid]  = a2;
            S.f.Bv[tid] = b2;
            S.f.C0[tid] = c0 + l2_b1[tid];
            S.f.C1[tid] = c1 + l2_b1[tid];
            S.f.W2[tid] = l2_w2[tid];
        }
        if (tid == 0) S.f.l2b2 = l2_b2[0];
        __syncthreads();
        if (tid < Sn) {
            int c = S.f.c3[tid];
            int s = -1;
            for (int u = tid + 1; u < Sn; ++u)
                if (S.f.c3[u] == c) { s = u; break; }
            S.f.succ[tid] = s;
            int rt = 1;
            for (int u = 0; u < tid; ++u)
                if (S.f.c3[u] == c) { rt = 0; break; }
            S.f.root[tid] = rt;
        }
        __syncthreads();
        {   // chain walk, 16-lane groups
            const int g  = tid >> 4;
            const int l  = tid & 15;
            const int j0 = l * 4;
            float A0=S.f.A[j0],  A1=S.f.A[j0+1],  A2=S.f.A[j0+2],  A3=S.f.A[j0+3];
            float B0=S.f.Bv[j0], B1=S.f.Bv[j0+1], B2=S.f.Bv[j0+2], B3=S.f.Bv[j0+3];
            float C00=S.f.C0[j0],C01=S.f.C0[j0+1],C02=S.f.C0[j0+2],C03=S.f.C0[j0+3];
            float C10=S.f.C1[j0],C11=S.f.C1[j0+1],C12=S.f.C1[j0+2],C13=S.f.C1[j0+3];
            float W0=S.f.W2[j0], W1=S.f.W2[j0+1], W2v=S.f.W2[j0+2],W3=S.f.W2[j0+3];
            float l2b2 = S.f.l2b2;
            for (int t0 = g; t0 < Sn; t0 += 16) {
                if (!S.f.root[t0]) continue;
                float beta = 0.f;
                int t = t0;
                while (t >= 0) {
                    float gam = S.f.gam[t];
                    int   r   = S.f.r[t];
                    float s = W0*fmaxf(A0*beta + B0*gam + (r ? C10 : C00), 0.f)
                            + W1*fmaxf(A1*beta + B1*gam + (r ? C11 : C01), 0.f)
                            + W2v*fmaxf(A2*beta + B2*gam + (r ? C12 : C02), 0.f)
                            + W3*fmaxf(A3*beta + B3*gam + (r ? C13 : C03), 0.f);
                    s += __shfl_xor(s, 1, 16);
                    s += __shfl_xor(s, 2, 16);
                    s += __shfl_xor(s, 4, 16);
                    s += __shfl_xor(s, 8, 16);
                    beta = s + l2b2;
                    if (l == 0) S.f.val[t] = beta;
                    t = S.f.succ[t];
                }
            }
        }
        __syncthreads();
        // forward-fill 50 rows x 16KB, contiguous per-block stream
        const int cA = tid*4, cB = 1024 + tid*4, cC = 2048 + tid*4, cD = 3072 + tid*4;
        float4 qA = make_float4(0.f,0.f,0.f,0.f), qB = qA, qC = qA, qD = qA;
        const int t0 = qt * 50;
        for (int t = 0; t < t0; ++t) {          // pre-scan (no stores)
            int cc = S.f.c3[t]; float v = S.f.val[t];
            UPD(qA, cA) UPD(qB, cB) UPD(qC, cC) UPD(qD, cD)
        }
        float* rowp = out_c3 + (size_t)b * Sn * NC3n + (size_t)t0 * NC3n;
        const bool doD = (tid < 232);
        for (int t = t0; t < t0 + 50; ++t) {
            int cc = S.f.c3[t]; float v = S.f.val[t];
            UPD(qA, cA) UPD(qB, cB) UPD(qC, cC) UPD(qD, cD)
            *(float4*)(rowp + cA) = qA;
            *(float4*)(rowp + cB) = qB;
            *(float4*)(rowp + cC) = qC;
            if (doD) *(float4*)(rowp + cD) = qD;
            rowp += NC3n;
        }
    }
}

extern "C" void kernel_launch(void* const* d_in, const int* in_sizes, int n_in,
                              void* d_out, int out_size, void* d_ws, size_t ws_size,
                              hipStream_t stream)
{
    const int*   c3_seq = (const int*)  d_in[0];
    const int*   d_seq  = (const int*)  d_in[1];
    const int*   r_seq  = (const int*)  d_in[2];
    const float* v_c3   = (const float*)d_in[3];
    const float* D_w    = (const float*)d_in[4];
    const float* v_d    = (const float*)d_in[5];
    const float* R_w    = (const float*)d_in[6];
    const float* W_ih   = (const float*)d_in[7];
    const float* W_hh   = (const float*)d_in[8];
    const float* b_ih   = (const float*)d_in[9];
    const float* b_hh   = (const float*)d_in[10];
    const float* l1_w1  = (const float*)d_in[11];
    const float* l1_b1  = (const float*)d_in[12];
    const float* l1_w2  = (const float*)d_in[13];
    const float* l1_b2  = (const float*)d_in[14];
    const float* l2_w1  = (const float*)d_in[15];
    const float* l2_b1  = (const float*)d_in[16];
    const float* l2_w2  = (const float*)d_in[17];
    const float* l2_b2  = (const float*)d_in[18];

    float* out_alpha = (float*)d_out;
    float* out_h     = out_alpha + Bn*Sn;
    float* out_c3    = out_h + (size_t)Bn*Sn*64;

    fused8_kernel<<<GRUB + FILLB, 256, 0, stream>>>(
        c3_seq, d_seq, r_seq, v_c3, D_w, v_d, R_w, W_ih, W_hh, b_ih, b_hh,
        l1_w1, l1_b1, l1_w2, l1_b2, l2_w1, l2_b1, l2_w2, l2_b2,
        out_alpha, out_h, out_c3);
}

// Round 17
// 151.088 us; speedup vs baseline: 1.6597x; 1.0590x over previous
//
#include <hip/hip_runtime.h>
#include <math.h>

#define Bn 128
#define Sn 200
#define NC3n 4000
#define GRUB Bn                 // 128 GRU blocks, 1 row each
#define FILLB (Bn * 4)          // 512 fill blocks, (b, quarter)

typedef float vf4 __attribute__((ext_vector_type(4)));

__device__ __forceinline__ float fexp(float x) { return __builtin_amdgcn_exp2f(x * 1.44269504f); }
__device__ __forceinline__ float frcp(float x) { return __builtin_amdgcn_rcpf(x); }
__device__ __forceinline__ float fsig(float x) { return frcp(1.f + fexp(-x)); }
__device__ __forceinline__ float rlanef(float v, int k) {
    return __int_as_float(__builtin_amdgcn_readlane(__float_as_int(v), k));
}
__device__ __forceinline__ void nt_store4(float* p, float4 q) {
    vf4 v; v.x = q.x; v.y = q.y; v.z = q.z; v.w = q.w;
    __builtin_nontemporal_store(v, (vf4*)p);
}

#define UPD(q, cbase) { int d = cc - (cbase); if ((unsigned)d < 4u) { \
    q.x = (d==0)?v:q.x; q.y = (d==1)?v:q.y; q.z = (d==2)?v:q.z; q.w = (d==3)?v:q.w; } }

struct GruLds {                 // ~69 KB
    float ring[2][16][64];      // out_h staging (8 KB)
    float pPart[Sn][68];        // per-lane mlp1 partials, padded rows (54.4 KB)
    float hbc[4][64];           // per-wave h broadcast strips
    float u[192], w0[192], w1[192];
    float hg[2][192];           // ping-pong W_hh@h + b_hh
    float gam[Sn];
    int   r[Sn];
};
struct FillLds {                // ~6.2 KB
    float gam[Sn], val[Sn];
    int   r[Sn], c3[Sn], succ[Sn], root[Sn];
    float A[64], Bv[64], C0[64], C1[64], W2[64];
    float l2b2;
};

__global__ __launch_bounds__(256, 2) void fused9_kernel(
    const int* __restrict__ c3_seq, const int* __restrict__ d_seq,
    const int* __restrict__ r_seq, const float* __restrict__ v_c3,
    const float* __restrict__ D_w, const float* __restrict__ v_d,
    const float* __restrict__ R_w, const float* __restrict__ W_ih,
    const float* __restrict__ W_hh, const float* __restrict__ b_ih,
    const float* __restrict__ b_hh,
    const float* __restrict__ l1_w1, const float* __restrict__ l1_b1,
    const float* __restrict__ l1_w2, const float* __restrict__ l1_b2,
    const float* __restrict__ l2_w1, const float* __restrict__ l2_b1,
    const float* __restrict__ l2_w2, const float* __restrict__ l2_b2,
    float* __restrict__ out_alpha, float* __restrict__ out_h,
    float* __restrict__ out_c3)
{
    __shared__ __align__(16) union { GruLds g; FillLds f; } S;

    const int tid = threadIdx.x;
    const int bid = blockIdx.x;

    if (bid < GRUB) {
        // ===== GRU + mlp1 + alpha: 1 row, 4 role waves, 1 barrier/step,
        // ZERO in-loop cross-lane ops (shfl chain removed -> deferred sum) =====
        __builtin_amdgcn_s_setprio(1);
        const int b    = bid;
        const int role = tid >> 6;          // 0=r,1=z,2=n,3=mlp1
        const int j    = tid & 63;

        if (tid < Sn) {
            S.g.gam[tid] = D_w[d_seq[b * Sn + tid]];
            S.g.r[tid]   = r_seq[b * Sn + tid];
        }
        // fold xg: u = W_ih[rho,:64]@v_d ; w0/w1 = W_ih[rho,64:]@R_w[r] + b_ih[rho]
        if (tid < 192) {
            const float4* rp  = (const float4*)(W_ih + (size_t)tid * 128);
            const float4* vd4 = (const float4*)v_d;
            const float4* q04 = (const float4*)R_w;
            const float4* q14 = (const float4*)(R_w + 64);
            float u = 0.f, w0 = 0.f, w1 = 0.f;
            #pragma unroll 4
            for (int k = 0; k < 16; ++k) {
                float4 a  = rp[k];
                float4 bb = rp[16 + k];
                float4 vd = vd4[k], q0 = q04[k], q1 = q14[k];
                u  += a.x*vd.x + a.y*vd.y + a.z*vd.z + a.w*vd.w;
                w0 += bb.x*q0.x + bb.y*q0.y + bb.z*q0.z + bb.w*q0.w;
                w1 += bb.x*q1.x + bb.y*q1.y + bb.z*q1.z + bb.w*q1.w;
            }
            float bih = b_ih[tid];
            S.g.u[tid]  = u;
            S.g.w0[tid] = w0 + bih;
            S.g.w1[tid] = w1 + bih;
        }
        // per-wave weight row: role<3 -> W_hh row role*64+j ; role==3 -> l1_w1 row j
        float w[64];
        {
            const float* src = (role < 3) ? (W_hh + (size_t)(role * 64 + j) * 64)
                                          : (l1_w1 + (size_t)j * 64);
            const float4* s4 = (const float4*)src;
            #pragma unroll
            for (int k = 0; k < 16; ++k) {
                float4 v = s4[k];
                w[4*k+0]=v.x; w[4*k+1]=v.y; w[4*k+2]=v.z; w[4*k+3]=v.w;
            }
        }
        // keep the weights live in VGPRs across the loop (no remat/sink)
        #pragma unroll
        for (int k = 0; k < 16; ++k)
            asm volatile("" : "+v"(w[4*k+0]), "+v"(w[4*k+1]), "+v"(w[4*k+2]), "+v"(w[4*k+3]));

        float bown = 0.f, l1b = 0.f, l1w2v = 0.f;
        if (role < 3) {
            bown = b_hh[role * 64 + j];
            S.g.hg[0][role * 64 + j] = bown;    // h0=0 -> hg(t=0)=b_hh
        } else {
            l1b = l1_b1[j]; l1w2v = l1_w2[j];
        }
        const float l1b2c = l1_b2[0];
        __syncthreads();                        // prologue barrier

        const float uj  = S.g.u[j],  u1  = S.g.u[64+j],  u2  = S.g.u[128+j];
        const float w00 = S.g.w0[j], w01 = S.g.w0[64+j], w02 = S.g.w0[128+j];
        const float w10 = S.g.w1[j], w11 = S.g.w1[64+j], w12 = S.g.w1[128+j];

        float vh = 0.f;
        float* outh_base = out_h + (size_t)b * Sn * 64;
        const int rloc = 4 * role + (j >> 4);
        const int cloc = (j & 15) * 4;

        for (int t = 0; t < Sn; ++t) {
            if (t && (t & 15) == 0) {           // flush completed ring half
                const int hb = ((t >> 4) & 1) ^ 1;
                float4 v4 = *(const float4*)&S.g.ring[hb][rloc][cloc];
                *(float4*)(outh_base + (size_t)(t - 16 + rloc) * 64 + cloc) = v4;
            }
            const int buf = t & 1;
            float gam = S.g.gam[t];
            int   r   = S.g.r[t];
            float hr = S.g.hg[buf][j], hz = S.g.hg[buf][64+j], hn = S.g.hg[buf][128+j];
            float rg = fsig(fmaf(gam, uj, r ? w10 : w00) + hr);
            float zg = fsig(fmaf(gam, u1, r ? w11 : w01) + hz);
            float e2 = fexp(2.f * (fmaf(gam, u2, r ? w12 : w02) + rg * hn));
            float ng = 1.f - 2.f * frcp(e2 + 1.f);   // tanh
            vh = (1.f - zg) * ng + zg * vh;
            // self-broadcast h: write strip, BATCH all 16 b128 reads (single wait)
            S.g.hbc[role][j] = vh;
            float4 hreg[16];
            #pragma unroll
            for (int k = 0; k < 16; ++k)
                hreg[k] = *(const float4*)&S.g.hbc[role][k * 4];
            __builtin_amdgcn_sched_barrier(0);  // keep loads batched above the fmas
            float a0=0.f, a1=0.f, a2=0.f, a3=0.f;
            #pragma unroll
            for (int k = 0; k < 16; ++k) {
                a0 = fmaf(w[4*k+0], hreg[k].x, a0);
                a1 = fmaf(w[4*k+1], hreg[k].y, a1);
                a2 = fmaf(w[4*k+2], hreg[k].z, a2);
                a3 = fmaf(w[4*k+3], hreg[k].w, a3);
            }
            float dot = (a0 + a1) + (a2 + a3);
            if (role < 3) {
                S.g.hg[buf ^ 1][role * 64 + j] = bown + dot;
            } else {
                // raw per-lane partial only — NO shfl chain in the loop
                S.g.pPart[t][j] = fmaxf(dot + l1b, 0.f) * l1w2v;
                S.g.ring[(t >> 4) & 1][t & 15][j] = vh;
            }
            __syncthreads();
        }
        if (role < 2) {                         // rows 192..199 from ring[0][0..7]
            float4 v4 = *(const float4*)&S.g.ring[0][rloc][cloc];
            *(float4*)(outh_base + (size_t)(192 + rloc) * 64 + cloc) = v4;
        }
        // deferred mlp1 sums + alpha chain (role 3)
        if (role == 3) {
            const int j3 = (j < 8) ? (192 + j) : 199;
            float4 s0 = make_float4(0.f,0.f,0.f,0.f), s1 = s0, s2 = s0, s3 = s0;
            const float4* p0 = (const float4*)&S.g.pPart[j][0];
            const float4* p1 = (const float4*)&S.g.pPart[64 + j][0];
            const float4* p2 = (const float4*)&S.g.pPart[128 + j][0];
            const float4* p3 = (const float4*)&S.g.pPart[j3][0];
            #pragma unroll
            for (int k = 0; k < 16; ++k) {
                float4 a = p0[k], bq = p1[k], c = p2[k], d = p3[k];
                s0.x += a.x;  s0.y += a.y;  s0.z += a.z;  s0.w += a.w;
                s1.x += bq.x; s1.y += bq.y; s1.z += bq.z; s1.w += bq.w;
                s2.x += c.x;  s2.y += c.y;  s2.z += c.z;  s2.w += c.w;
                s3.x += d.x;  s3.y += d.y;  s3.z += d.z;  s3.w += d.w;
            }
            float an0 = ((s0.x+s0.y)+(s0.z+s0.w)) + l1b2c;
            float an1 = ((s1.x+s1.y)+(s1.z+s1.w)) + l1b2c;
            float an2 = ((s2.x+s2.y)+(s2.z+s2.w)) + l1b2c;
            float an3 = ((s3.x+s3.y)+(s3.z+s3.w)) + l1b2c;
            float g0 = S.g.gam[j],       g1 = S.g.gam[64 + j];
            float g2 = S.g.gam[128 + j], g3 = S.g.gam[j3];
            int   r0 = S.g.r[j],         r1 = S.g.r[64 + j];
            int   r2 = S.g.r[128 + j],   r3 = S.g.r[j3];
            float alpha = 0.f;
            float* oa = out_alpha + b * Sn;
            for (int t = 0; t < Sn; ++t) {
                const int q = t >> 6, l = t & 63;
                float an, g; int rr;
                if (q == 0)      { an = rlanef(an0,l); g = rlanef(g0,l); rr = __builtin_amdgcn_readlane(r0,l); }
                else if (q == 1) { an = rlanef(an1,l); g = rlanef(g1,l); rr = __builtin_amdgcn_readlane(r1,l); }
                else if (q == 2) { an = rlanef(an2,l); g = rlanef(g2,l); rr = __builtin_amdgcn_readlane(r2,l); }
                else             { an = rlanef(an3,l); g = rlanef(g3,l); rr = __builtin_amdgcn_readlane(r3,l); }
                bool cond = (alpha - g) >= 0.f;
                alpha = rr ? (cond ? an : alpha) : (cond ? alpha : an);
                if (j == 0) oa[t] = alpha;
            }
        }
    } else {
        // ===== C3 chain + contiguous forward-fill: one (row, quarter) =====
        const int fb = bid - GRUB;
        const int b  = fb >> 2;
        const int qt = fb & 3;
        if (tid < Sn) {
            S.f.gam[tid] = D_w[d_seq[b*Sn + tid]];
            S.f.r[tid]   = r_seq[b*Sn + tid];
            S.f.c3[tid]  = c3_seq[b*Sn + tid];
        }
        if (tid < 64) {
            const float4* row4 = (const float4*)(l2_w1 + (size_t)tid * 192);
            const float4* vc4  = (const float4*)v_c3;
            const float4* vd4  = (const float4*)v_d;
            const float4* q04  = (const float4*)R_w;
            const float4* q14  = (const float4*)(R_w + 64);
            float a2=0.f, b2=0.f, c0=0.f, c1=0.f;
            #pragma unroll 4
            for (int k = 0; k < 16; ++k) {
                float4 ra = row4[k], rb = row4[16+k], rc = row4[32+k];
                float4 vc = vc4[k], vd = vd4[k], q0 = q04[k], q1 = q14[k];
                a2 += ra.x*vc.x + ra.y*vc.y + ra.z*vc.z + ra.w*vc.w;
                b2 += rb.x*vd.x + rb.y*vd.y + rb.z*vd.z + rb.w*vd.w;
                c0 += rc.x*q0.x + rc.y*q0.y + rc.z*q0.z + rc.w*q0.w;
                c1 += rc.x*q1.x + rc.y*q1.y + rc.z*q1.z + rc.w*q1.w;
            }
            S.f.A[tid]  = a2;
            S.f.Bv[tid] = b2;
            S.f.C0[tid] = c0 + l2_b1[tid];
            S.f.C1[tid] = c1 + l2_b1[tid];
            S.f.W2[tid] = l2_w2[tid];
        }
        if (tid == 0) S.f.l2b2 = l2_b2[0];
        __syncthreads();
        if (tid < Sn) {
            int c = S.f.c3[tid];
            int s = -1;
            for (int u = tid + 1; u < Sn; ++u)
                if (S.f.c3[u] == c) { s = u; break; }
            S.f.succ[tid] = s;
            int rt = 1;
            for (int u = 0; u < tid; ++u)
                if (S.f.c3[u] == c) { rt = 0; break; }
            S.f.root[tid] = rt;
        }
        __syncthreads();
        {   // chain walk, 16-lane groups
            const int g  = tid >> 4;
            const int l  = tid & 15;
            const int j0 = l * 4;
            float A0=S.f.A[j0],  A1=S.f.A[j0+1],  A2=S.f.A[j0+2],  A3=S.f.A[j0+3];
            float B0=S.f.Bv[j0], B1=S.f.Bv[j0+1], B2=S.f.Bv[j0+2], B3=S.f.Bv[j0+3];
            float C00=S.f.C0[j0],C01=S.f.C0[j0+1],C02=S.f.C0[j0+2],C03=S.f.C0[j0+3];
            float C10=S.f.C1[j0],C11=S.f.C1[j0+1],C12=S.f.C1[j0+2],C13=S.f.C1[j0+3];
            float W0=S.f.W2[j0], W1=S.f.W2[j0+1], W2v=S.f.W2[j0+2],W3=S.f.W2[j0+3];
            float l2b2 = S.f.l2b2;
            for (int t0 = g; t0 < Sn; t0 += 16) {
                if (!S.f.root[t0]) continue;
                float beta = 0.f;
                int t = t0;
                while (t >= 0) {
                    float gam = S.f.gam[t];
                    int   r   = S.f.r[t];
                    float s = W0*fmaxf(A0*beta + B0*gam + (r ? C10 : C00), 0.f)
                            + W1*fmaxf(A1*beta + B1*gam + (r ? C11 : C01), 0.f)
                            + W2v*fmaxf(A2*beta + B2*gam + (r ? C12 : C02), 0.f)
                            + W3*fmaxf(A3*beta + B3*gam + (r ? C13 : C03), 0.f);
                    s += __shfl_xor(s, 1, 16);
                    s += __shfl_xor(s, 2, 16);
                    s += __shfl_xor(s, 4, 16);
                    s += __shfl_xor(s, 8, 16);
                    beta = s + l2b2;
                    if (l == 0) S.f.val[t] = beta;
                    t = S.f.succ[t];
                }
            }
        }
        __syncthreads();
        // forward-fill 50 rows x 16KB, contiguous per-block stream (nontemporal)
        const int cA = tid*4, cB = 1024 + tid*4, cC = 2048 + tid*4, cD = 3072 + tid*4;
        float4 qA = make_float4(0.f,0.f,0.f,0.f), qB = qA, qC = qA, qD = qA;
        const int t0 = qt * 50;
        for (int t = 0; t < t0; ++t) {          // pre-scan (no stores)
            int cc = S.f.c3[t]; float v = S.f.val[t];
            UPD(qA, cA) UPD(qB, cB) UPD(qC, cC) UPD(qD, cD)
        }
        float* rowp = out_c3 + (size_t)b * Sn * NC3n + (size_t)t0 * NC3n;
        const bool doD = (tid < 232);
        for (int t = t0; t < t0 + 50; ++t) {
            int cc = S.f.c3[t]; float v = S.f.val[t];
            UPD(qA, cA) UPD(qB, cB) UPD(qC, cC) UPD(qD, cD)
            nt_store4(rowp + cA, qA);
            nt_store4(rowp + cB, qB);
            nt_store4(rowp + cC, qC);
            if (doD) nt_store4(rowp + cD, qD);
            rowp += NC3n;
        }
    }
}

extern "C" void kernel_launch(void* const* d_in, const int* in_sizes, int n_in,
                              void* d_out, int out_size, void* d_ws, size_t ws_size,
                              hipStream_t stream)
{
    const int*   c3_seq = (const int*)  d_in[0];
    const int*   d_seq  = (const int*)  d_in[1];
    const int*   r_seq  = (const int*)  d_in[2];
    const float* v_c3   = (const float*)d_in[3];
    const float* D_w    = (const float*)d_in[4];
    const float* v_d    = (const float*)d_in[5];
    const float* R_w    = (const float*)d_in[6];
    const float* W_ih   = (const float*)d_in[7];
    const float* W_hh   = (const float*)d_in[8];
    const float* b_ih   = (const float*)d_in[9];
    const float* b_hh   = (const float*)d_in[10];
    const float* l1_w1  = (const float*)d_in[11];
    const float* l1_b1  = (const float*)d_in[12];
    const float* l1_w2  = (const float*)d_in[13];
    const float* l1_b2  = (const float*)d_in[14];
    const float* l2_w1  = (const float*)d_in[15];
    const float* l2_b1  = (const float*)d_in[16];
    const float* l2_w2  = (const float*)d_in[17];
    const float* l2_b2  = (const float*)d_in[18];

    float* out_alpha = (float*)d_out;
    float* out_h     = out_alpha + Bn*Sn;
    float* out_c3    = out_h + (size_t)Bn*Sn*64;

    fused9_kernel<<<GRUB + FILLB, 256, 0, stream>>>(
        c3_seq, d_seq, r_seq, v_c3, D_w, v_d, R_w, W_ih, W_hh, b_ih, b_hh,
        l1_w1, l1_b1, l1_w2, l1_b2, l2_w1, l2_b1, l2_w2, l2_b2,
        out_alpha, out_h, out_c3);
}